// Round 2
// baseline (234.691 us; speedup 1.0000x reference)
//
#include <hip/hip_runtime.h>
#include <math.h>

#define HD   768
#define NR   8
#define NB   8
#define SL   512
#define NE   64
#define NTOK 4096      // NB*SL
#define NSR  32768     // NR*NTOK

__device__ __forceinline__ float wred(float v) {
  #pragma unroll
  for (int m = 32; m >= 1; m >>= 1) v += __shfl_xor(v, m, 64);
  return v;
}

__device__ __forceinline__ float dot12(const float4 a0, const float4 a1, const float4 a2,
                                       const float* __restrict__ w, int lane) {
  const float4 w0 = *reinterpret_cast<const float4*>(w + lane * 4);
  const float4 w1 = *reinterpret_cast<const float4*>(w + 256 + lane * 4);
  const float4 w2 = *reinterpret_cast<const float4*>(w + 512 + lane * 4);
  float s = 0.f;
  s = fmaf(a0.x, w0.x, s); s = fmaf(a0.y, w0.y, s); s = fmaf(a0.z, w0.z, s); s = fmaf(a0.w, w0.w, s);
  s = fmaf(a1.x, w1.x, s); s = fmaf(a1.y, w1.y, s); s = fmaf(a1.z, w1.z, s); s = fmaf(a1.w, w1.w, s);
  s = fmaf(a2.x, w2.x, s); s = fmaf(a2.y, w2.y, s); s = fmaf(a2.z, w2.z, s); s = fmaf(a2.w, w2.w, s);
  return s;
}

// One chain step k: reads u_k (768) for both chains (single / multi),
// writes v_k = Wa u_k, u_{k+1} = Wb u_k, and bu_k = b_ans . u_k.
// W_ans is [1536,768] row-major; rows 0..767 = Wa, 768..1535 = Wb.
__global__ __launch_bounds__(256) void chain_kernel(
    const float* __restrict__ W_ans, const float* __restrict__ b_ans,
    const float* __restrict__ uS_in, const float* __restrict__ uM_in,
    float* __restrict__ vS_out, float* __restrict__ vM_out,
    float* __restrict__ uS_out, float* __restrict__ uM_out,
    float* __restrict__ buS, float* __restrict__ buM)
{
  const int wid  = blockIdx.x * 4 + (threadIdx.x >> 6);
  const int lane = threadIdx.x & 63;
  if (wid < 3072) {
    const int cm  = (wid >= 1536);
    const int row = wid - (cm ? 1536 : 0);
    const float* u = cm ? uM_in : uS_in;
    const float* wr = W_ans + (size_t)row * HD;
    const float4 a0 = *reinterpret_cast<const float4*>(wr + lane * 4);
    const float4 a1 = *reinterpret_cast<const float4*>(wr + 256 + lane * 4);
    const float4 a2 = *reinterpret_cast<const float4*>(wr + 512 + lane * 4);
    float acc = wred(dot12(a0, a1, a2, u, lane));
    if (lane == 0) {
      if (row < HD) { (cm ? vM_out : vS_out)[row] = acc; }
      else          { (cm ? uM_out : uS_out)[row - HD] = acc; }
    }
  } else if (wid < 3074) {
    const float* u = (wid == 3073) ? uM_in : uS_in;
    const float4 a0 = *reinterpret_cast<const float4*>(b_ans + lane * 4);
    const float4 a1 = *reinterpret_cast<const float4*>(b_ans + 256 + lane * 4);
    const float4 a2 = *reinterpret_cast<const float4*>(b_ans + 512 + lane * 4);
    float acc = wred(dot12(a0, a1, a2, u, lane));
    if (lane == 0) { if (wid == 3073) *buM = acc; else *buS = acc; }
  }
}

// Waves 0..32767: stream sr rows -> a_s, a_m.  Waves 32768..36863: per-token dots.
__global__ __launch_bounds__(256) void dots_kernel(
    const float* __restrict__ sr, const float* __restrict__ tok, const float* __restrict__ ent,
    const float* __restrict__ Wsing, const float* __restrict__ Wmult,
    const float* __restrict__ vS, const float* __restrict__ vM,
    float* __restrict__ as_out, float* __restrict__ am_out,
    float* __restrict__ ps_out, float* __restrict__ pm_out,
    float* __restrict__ dts_out, float* __restrict__ dem_out)
{
  const int wid  = blockIdx.x * 4 + (threadIdx.x >> 6);
  const int lane = threadIdx.x & 63;
  if (wid < NSR) {
    const float* row = sr + (size_t)wid * HD;
    const float4 x0 = *reinterpret_cast<const float4*>(row + lane * 4);
    const float4 x1 = *reinterpret_cast<const float4*>(row + 256 + lane * 4);
    const float4 x2 = *reinterpret_cast<const float4*>(row + 512 + lane * 4);
    float aS = wred(dot12(x0, x1, x2, Wsing, lane));   // W_single[0:768]
    float aM = wred(dot12(x0, x1, x2, Wmult, lane));   // W_multi[0:768]
    if (lane == 0) { as_out[wid] = aS; am_out[wid] = aM; }
  } else if (wid < NSR + NTOK) {
    const int t = wid - NSR;
    const float* tr = tok + (size_t)t * HD;
    const float* er = ent + (size_t)t * HD;
    const float4 t0 = *reinterpret_cast<const float4*>(tr + lane * 4);
    const float4 t1 = *reinterpret_cast<const float4*>(tr + 256 + lane * 4);
    const float4 t2 = *reinterpret_cast<const float4*>(tr + 512 + lane * 4);
    const float4 e0 = *reinterpret_cast<const float4*>(er + lane * 4);
    const float4 e1 = *reinterpret_cast<const float4*>(er + 256 + lane * 4);
    const float4 e2v = *reinterpret_cast<const float4*>(er + 512 + lane * 4);
    float dts = wred(dot12(t0, t1, t2, Wsing + HD, lane));   // tok . ws_tok
    float dem = wred(dot12(e0, e1, e2v, Wmult + HD, lane));  // ent . wm_ent
    float psv[7], pmv[7];
    #pragma unroll
    for (int k = 0; k < 7; ++k) {
      psv[k] = wred(dot12(t0, t1, t2, vS + k * HD, lane));
      pmv[k] = wred(dot12(t0, t1, t2, vM + k * HD, lane));
    }
    if (lane == 0) {
      dts_out[t] = dts; dem_out[t] = dem;
      #pragma unroll
      for (int k = 0; k < 7; ++k) { ps_out[k * NTOK + t] = psv[k]; pm_out[k * NTOK + t] = pmv[k]; }
    }
  }
}

// One block per batch b; thread = token s. Scalar recurrence over r + LDS segment-max.
__global__ __launch_bounds__(512) void step_kernel(
    const float* __restrict__ labels, const int* __restrict__ e2t, const int* __restrict__ t2e,
    const float* __restrict__ ps, const float* __restrict__ pm,
    const float* __restrict__ dts, const float* __restrict__ dem,
    const float* __restrict__ as_, const float* __restrict__ am_,
    const float* __restrict__ buS, const float* __restrict__ buM,
    const float* __restrict__ b_single, const float* __restrict__ b_multi,
    float* __restrict__ out, double* __restrict__ partial_bce)
{
  __shared__ unsigned sc[NR][NE];          // 8 x 64, one buffer per step
  const int s = threadIdx.x;
  const int b = blockIdx.x;
  const int t = b * SL + s;
  reinterpret_cast<unsigned*>(sc)[s] = 0u; // 512 entries exactly
  float psv[7], pmv[7], asv[8], amv[8], buSv[7], buMv[7];
  #pragma unroll
  for (int k = 0; k < 7; ++k) { psv[k] = ps[k * NTOK + t]; pmv[k] = pm[k * NTOK + t]; }
  #pragma unroll
  for (int r = 0; r < 8; ++r) { asv[r] = as_[r * NTOK + t]; amv[r] = am_[r * NTOK + t]; }
  #pragma unroll
  for (int k = 0; k < 7; ++k) { buSv[k] = buS[k]; buMv[k] = buM[k]; }
  const float dtsv = dts[t], demv = dem[t];
  const float b1 = b_single[0], b2 = b_multi[0];
  const int e2 = e2t[t] & (NE - 1);
  const int t2 = t2e[t] & (NE - 1);
  __syncthreads();

  float m[8];
  float cs = 0.f, cmv = 0.f;
  double bsum = 0.0;
  #pragma unroll
  for (int r = 0; r < 8; ++r) {
    float As = cs, Am = cmv;
    #pragma unroll
    for (int j = 0; j < r; ++j) {
      As = fmaf(m[j], psv[r - 1 - j], As);
      Am = fmaf(m[j], pmv[r - 1 - j], Am);
    }
    const float xs = asv[r] + dtsv + As + b1;
    const float xm = amv[r] + demv + Am + b2;
    const float sing = 1.f / (1.f + expf(-xs));
    const float mult = 1.f / (1.f + expf(-xm));
    atomicMax(&sc[r][e2], __float_as_uint(mult));   // mult > 0: uint order == float order
    __syncthreads();
    const float pred = __uint_as_float(sc[r][t2]);  // empty segments stay 0.0f == max(.,0)
    const float merged = fmaxf(sing, pred);
    m[r] = merged;
    out[1 + r * NTOK + t] = merged;
    const float lab = labels[r * NTOK + t];
    const float p = fminf(fmaxf(merged, 1e-7f), 1.0f - 1e-7f);
    bsum += (double)(-(lab * logf(p) + (1.f - lab) * log1pf(-p)));
    if (r < 7) { cs += buSv[r]; cmv += buMv[r]; }
  }
  // block reduction of bsum
  #pragma unroll
  for (int off = 32; off >= 1; off >>= 1) bsum += __shfl_xor(bsum, off, 64);
  __shared__ double wsum[8];
  if ((threadIdx.x & 63) == 0) wsum[threadIdx.x >> 6] = bsum;
  __syncthreads();
  if (threadIdx.x == 0) {
    double tot = 0.0;
    #pragma unroll
    for (int i = 0; i < 8; ++i) tot += wsum[i];
    partial_bce[b] = tot;
  }
}

__global__ __launch_bounds__(256) void finalize_kernel(
    const float* __restrict__ mask, const double* __restrict__ partial_bce, float* __restrict__ out)
{
  const int tid = threadIdx.x;
  float sm = 0.f;
  for (int i = tid; i < NTOK; i += 256) sm += mask[i];
  sm = wred(sm);
  __shared__ float w4[4];
  if ((tid & 63) == 0) w4[tid >> 6] = sm;
  __syncthreads();
  if (tid == 0) {
    const float msum = w4[0] + w4[1] + w4[2] + w4[3];
    double tot = 0.0;
    #pragma unroll
    for (int i = 0; i < 8; ++i) tot += partial_bce[i];
    out[0] = (float)(tot * (double)msum / 4096.0);
  }
}

extern "C" void kernel_launch(void* const* d_in, const int* in_sizes, int n_in,
                              void* d_out, int out_size, void* d_ws, size_t ws_size,
                              hipStream_t stream) {
  (void)in_sizes; (void)n_in; (void)out_size; (void)ws_size;
  const float* labels = (const float*)d_in[0];
  const float* sr     = (const float*)d_in[1];
  const float* tok    = (const float*)d_in[2];
  const float* ent    = (const float*)d_in[3];
  const float* mask   = (const float*)d_in[4];
  const int*   e2t    = (const int*)d_in[5];
  const int*   t2e    = (const int*)d_in[6];
  const float* Wsing  = (const float*)d_in[7];
  const float* bsing  = (const float*)d_in[8];
  const float* Wmult  = (const float*)d_in[9];
  const float* bmult  = (const float*)d_in[10];
  const float* Wans   = (const float*)d_in[11];
  const float* bans   = (const float*)d_in[12];

  float* ws  = (float*)d_ws;
  float* uS  = ws;                 // [8][768] (slot 0 unused)
  float* uM  = uS + 8 * HD;        // [8][768]
  float* vS  = uM + 8 * HD;        // [7][768]
  float* vM  = vS + 7 * HD;        // [7][768]
  float* buS = vM + 7 * HD;        // [8]
  float* buM = buS + 8;            // [8]
  float* ps  = buM + 8;            // [7][4096]
  float* pm  = ps + 7 * NTOK;      // [7][4096]
  float* dts = pm + 7 * NTOK;      // [4096]
  float* dem = dts + NTOK;         // [4096]
  float* as_ = dem + NTOK;         // [8][4096]
  float* am_ = as_ + 8 * NTOK;     // [8][4096]
  double* pb = (double*)(am_ + 8 * NTOK); // [8] (8-byte aligned: even float offset)

  for (int k = 0; k < 7; ++k) {
    const float* uSin = (k == 0) ? (Wsing + 2 * HD) : (uS + k * HD);
    const float* uMin = (k == 0) ? (Wmult + 2 * HD) : (uM + k * HD);
    chain_kernel<<<769, 256, 0, stream>>>(Wans, bans, uSin, uMin,
        vS + k * HD, vM + k * HD, uS + (k + 1) * HD, uM + (k + 1) * HD,
        buS + k, buM + k);
  }
  dots_kernel<<<9216, 256, 0, stream>>>(sr, tok, ent, Wsing, Wmult, vS, vM,
        as_, am_, ps, pm, dts, dem);
  step_kernel<<<8, 512, 0, stream>>>(labels, e2t, t2e, ps, pm, dts, dem,
        as_, am_, buS, buM, bsing, bmult, (float*)d_out, pb);
  finalize_kernel<<<1, 256, 0, stream>>>(mask, pb, (float*)d_out);
}